// Round 21
// baseline (39.077 us; speedup 1.0000x reference)
//
#include <hip/hip_runtime.h>

// ChamferDistance: B=4, N=M=8192, fp32 3-D points.
// R21: 8 waves/SIMD. R20 (4 waves/SIMD) was the first win since R5
// (36.3 -> 30.2 µs): TLP is the lever — issue-sum ~8 µs vs 30 wall says
// latency is still exposed ~3x. Max occupancy needs the <=64-VGPR bucket
// (m69: 8/4/2 waves at 64/128/256):
//  - col-split 4: wave = row-tile (w&1) x col-quarter (w>>1), 8 tiles/stage;
//    block = 512 thr owns 64 rows; grid 1024 = 4 blocks/CU (LDS 128 KB).
//  - live set < 64 regs: NO min3 pairing (needs 32 acc regs live) ->
//    sequential single acc + fmin (~56 live). launch_bounds(512,8).
//  - quarter-combine via LDS [q][rt][r][lane] (conflict-free), q=0 stores.
// Math verified since R4 (absmax 0.0156): d = n1+n2-2x.y, hi/lo bf16 K=16;
// C layout 32x32: col=lane&31, row=(r&3)+8*(r>>2)+4*(lane>>5).

typedef short  short8 __attribute__((ext_vector_type(8)));
typedef float  f32x16 __attribute__((ext_vector_type(16)));

#define B_       4
#define NPT      8192
#define THREADS  512
#define NROWBLK  128             // 64 rows per block
#define STAGEPTS 1024            // B points per LDS stage (32 KB packed)
#define NSTAGE   (NPT / STAGEPTS)    // 8
#define PINF_I   0x7f800000

__device__ __forceinline__ unsigned short f2bf(float x) {
    unsigned u = __float_as_uint(x);
    u += 0x7fff + ((u >> 16) & 1);
    return (unsigned short)(u >> 16);
}
__device__ __forceinline__ float bf2f(unsigned short b) {
    return __uint_as_float(((unsigned)b) << 16);
}
#define PK2(a, b) ((((unsigned)(b)) << 16) | (unsigned)(a))

// Pack one row-point into the lane's A-fragment half (kg = lane>>5).
__device__ __forceinline__ short8 packA(const float* __restrict__ p, int kg) {
    const unsigned short one = 0x3f80;
    float x0 = p[0], x1 = p[1], x2 = p[2];
    unsigned short h0 = f2bf(x0), h1 = f2bf(x1), h2 = f2bf(x2);
    unsigned short l0 = f2bf(x0 - bf2f(h0)), l1 = f2bf(x1 - bf2f(h1)), l2 = f2bf(x2 - bf2f(h2));
    unsigned short m0 = f2bf(-2.f * bf2f(h0)), m1 = f2bf(-2.f * bf2f(h1)), m2 = f2bf(-2.f * bf2f(h2));
    unsigned short q0 = f2bf(-2.f * bf2f(l0)), q1 = f2bf(-2.f * bf2f(l1)), q2 = f2bf(-2.f * bf2f(l2));
    float n = x0*x0 + x1*x1 + x2*x2;
    unsigned short nh = f2bf(n), nl = f2bf(n - bf2f(nh));
    short8 r;
    if (kg == 0) {
        r[0] = (short)m0; r[1] = (short)m1; r[2] = (short)m2; r[3] = (short)q0;
        r[4] = (short)q1; r[5] = (short)q2; r[6] = (short)m0; r[7] = (short)m1;
    } else {
        r[0] = (short)m2; r[1] = (short)nh; r[2] = (short)nl; r[3] = (short)one;
        r[4] = (short)one; r[5] = 0; r[6] = 0; r[7] = 0;
    }
    return r;
}

__global__ __launch_bounds__(THREADS, 8)   // <=64-VGPR bucket -> 8 waves/SIMD
void cd_fused(const float* __restrict__ xyz1, const float* __restrict__ xyz2,
              float* __restrict__ out) {
    __shared__ uint4 ysh[STAGEPTS * 2];    // 32 KB: split-K packed B stage

    int bid = blockIdx.x;
    const int rb   = bid & (NROWBLK - 1);  bid >>= 7;
    const int b    = bid & (B_ - 1);       bid >>= 2;
    const int pass = bid;                   // 0: dist1 (rows=cloud1), 1: dist2

    const float* __restrict__ xa = pass ? xyz2 : xyz1;   // row cloud
    const float* __restrict__ xb = pass ? xyz1 : xyz2;   // col cloud
    float* __restrict__ o = out + (size_t)pass * B_ * NPT;

    const int tid  = threadIdx.x;
    const int lane = tid & 63;
    const int w    = tid >> 6;             // 0..7
    const int rt   = w & 1;                // row-tile within block (2)
    const int q    = w >> 1;               // column quarter (0..3)
    const int l31  = lane & 31;
    const int kg   = lane >> 5;
    const unsigned short one = 0x3f80;

    const size_t bbase = (size_t)b * NPT;
    const int    myRow = rb * 64 + rt * 32;

    // In-register A fragment: lane packs its own row, keeps its k-half.
    short8 afrag = packA(xa + (bbase + myRow + l31) * 3, kg);

    f32x16 rmin;
    #pragma unroll
    for (int r = 0; r < 16; ++r) rmin[r] = __int_as_float(PINF_I);

    const unsigned short* bsh = (const unsigned short*)ysh;

    for (int s = 0; s < NSTAGE; ++s) {
        // Pack 1024 B points into LDS (2 per thread), split-K layout.
        #pragma unroll
        for (int k = 0; k < 2; ++k) {
            const int p = k * THREADS + tid;
            const float* yp = xb + (bbase + (size_t)s * STAGEPTS + p) * 3;
            float y0 = yp[0], y1 = yp[1], y2 = yp[2];
            unsigned short h0 = f2bf(y0), h1 = f2bf(y1), h2 = f2bf(y2);
            unsigned short l0 = f2bf(y0 - bf2f(h0));
            unsigned short l1 = f2bf(y1 - bf2f(h1));
            unsigned short l2 = f2bf(y2 - bf2f(h2));
            float n = y0*y0 + y1*y1 + y2*y2;
            unsigned short nh = f2bf(n), nl = f2bf(n - bf2f(nh));
            const int g = p >> 5, sl = p & 31;
            ysh[g * 64 + sl]      = make_uint4(PK2(h0, h1), PK2(h2, h0), PK2(h1, h2), PK2(l0, l1));
            ysh[g * 64 + 32 + sl] = make_uint4(PK2(l2, one), PK2(one, nh), PK2(nl, 0), PK2(0, 0));
        }
        __syncthreads();

        // This wave's column quarter: 8 tiles of pure LDS compute.
        // Single acc live (register budget); fmin immediate; TLP hides latency.
        #pragma unroll
        for (int i = 0; i < 8; ++i) {
            const int t = q * 8 + i;
            short8 bf = *(const short8*)(bsh + (size_t)t * 512 + kg * 256 + l31 * 8);
            f32x16 z = {0.f};
            f32x16 acc = __builtin_amdgcn_mfma_f32_32x32x16_bf16(afrag, bf, z, 0, 0, 0);
            #pragma unroll
            for (int r = 0; r < 16; ++r) rmin[r] = fminf(rmin[r], acc[r]);
        }
        __syncthreads();
    }

    // Cross-quarter combine via LDS: q>0 write [q-1][rt][r][lane]; q==0 reads.
    float* csh = (float*)ysh;              // 3*2*16*64 floats = 24 KB
    if (q != 0) {
        #pragma unroll
        for (int r = 0; r < 16; ++r)
            csh[((q - 1) * 2 + rt) * 1024 + r * 64 + lane] = rmin[r];
    }
    __syncthreads();
    if (q == 0) {
        #pragma unroll
        for (int r = 0; r < 16; ++r) {
            float v = rmin[r];
            v = fminf(v, csh[(0 * 2 + rt) * 1024 + r * 64 + lane]);
            v = fminf(v, csh[(1 * 2 + rt) * 1024 + r * 64 + lane]);
            v = fminf(v, csh[(2 * 2 + rt) * 1024 + r * 64 + lane]);
            v = fminf(v, __shfl_xor(v, 1, 64));
            v = fminf(v, __shfl_xor(v, 2, 64));
            v = fminf(v, __shfl_xor(v, 4, 64));
            v = fminf(v, __shfl_xor(v, 8, 64));
            v = fminf(v, __shfl_xor(v, 16, 64));
            if (l31 == 0) {
                int row = myRow + (r & 3) + 8 * (r >> 2) + 4 * kg;
                o[bbase + row] = fmaxf(v, 0.f);
            }
        }
    }
}

extern "C" void kernel_launch(void* const* d_in, const int* in_sizes, int n_in,
                              void* d_out, int out_size, void* d_ws, size_t ws_size,
                              hipStream_t stream) {
    const float* xyz1 = (const float*)d_in[0];
    const float* xyz2 = (const float*)d_in[1];
    // ONE launch, no workspace, no init, no atomics.
    cd_fused<<<2 * B_ * NROWBLK, THREADS, 0, stream>>>(xyz1, xyz2, (float*)d_out);
}

// Round 22
// 33.306 us; speedup vs baseline: 1.1733x; 1.1733x over previous
//
#include <hip/hip_runtime.h>

// ChamferDistance: B=4, N=M=8192, fp32 3-D points.
// R22: R20 geometry + PRE-PACKED B + DMA staging.
// R21 post-mortem: 8 waves/SIMD regressed (30.2->39.1) because doubling the
// grid doubled the redundant per-block B-pack (8.4M packs, VALUBusy 40%).
// Pack work is now first-order. This round keeps R20's winning shape
// (512 thr, 128 rows/block, col-split 2, min3 pairing, 4 waves/SIMD) and
// deletes the in-kernel B-pack: a tiny kernel pre-packs both clouds' B-forms
// once (65k packs, 64x less), and the hot kernel stages each 32 KB chunk via
// 4x global_load_lds(16B)/thread — pure DMA, zero VALU, no f2bf/ds_write.
// Extra launch costs ~1.6 µs (R18 vs R19 delta).
// Math verified since R4 (absmax 0.0156): d = n1+n2-2x.y, hi/lo bf16 K=16;
// B-form split-K per 32-pt group (proven conflict-free); C layout 32x32:
// col=lane&31, row=(r&3)+8*(r>>2)+4*(lane>>5). Direct store (block owns
// its 128 rows completely), no atomics, no out-init.

typedef short  short8 __attribute__((ext_vector_type(8)));
typedef float  f32x16 __attribute__((ext_vector_type(16)));

#define B_       4
#define NPT      8192
#define THREADS  512
#define NROWBLK  64              // 128 rows per block
#define STAGEPTS 1024            // B points per LDS stage (32 KB packed)
#define NSTAGE   (NPT / STAGEPTS)    // 8
#define PINF_I   0x7f800000

__device__ __forceinline__ unsigned short f2bf(float x) {
    unsigned u = __float_as_uint(x);
    u += 0x7fff + ((u >> 16) & 1);
    return (unsigned short)(u >> 16);
}
__device__ __forceinline__ float bf2f(unsigned short b) {
    return __uint_as_float(((unsigned)b) << 16);
}
#define PK2(a, b) ((((unsigned)(b)) << 16) | (unsigned)(a))

// Tiny pre-pack: both clouds -> B-form split-K (scanned-side layout).
__global__ __launch_bounds__(256)
void cd_packB(const float* __restrict__ xyz1, const float* __restrict__ xyz2,
              unsigned short* __restrict__ B1, unsigned short* __restrict__ B2) {
    int i = blockIdx.x * 256 + threadIdx.x;
    if (i >= B_ * NPT) return;
    const unsigned short one = 0x3f80;
    const size_t bidx = ((size_t)(i >> 5)) * 64 + (i & 31);
    {
        float y0 = xyz1[3*i], y1 = xyz1[3*i+1], y2 = xyz1[3*i+2];
        unsigned short h0 = f2bf(y0), h1 = f2bf(y1), h2 = f2bf(y2);
        unsigned short l0 = f2bf(y0 - bf2f(h0)), l1 = f2bf(y1 - bf2f(h1)), l2 = f2bf(y2 - bf2f(h2));
        float n = y0*y0 + y1*y1 + y2*y2;
        unsigned short nh = f2bf(n), nl = f2bf(n - bf2f(nh));
        ((uint4*)B1)[bidx]      = make_uint4(PK2(h0, h1), PK2(h2, h0), PK2(h1, h2), PK2(l0, l1));
        ((uint4*)B1)[bidx + 32] = make_uint4(PK2(l2, one), PK2(one, nh), PK2(nl, 0), PK2(0, 0));
    }
    {
        float y0 = xyz2[3*i], y1 = xyz2[3*i+1], y2 = xyz2[3*i+2];
        unsigned short h0 = f2bf(y0), h1 = f2bf(y1), h2 = f2bf(y2);
        unsigned short l0 = f2bf(y0 - bf2f(h0)), l1 = f2bf(y1 - bf2f(h1)), l2 = f2bf(y2 - bf2f(h2));
        float n = y0*y0 + y1*y1 + y2*y2;
        unsigned short nh = f2bf(n), nl = f2bf(n - bf2f(nh));
        ((uint4*)B2)[bidx]      = make_uint4(PK2(h0, h1), PK2(h2, h0), PK2(h1, h2), PK2(l0, l1));
        ((uint4*)B2)[bidx + 32] = make_uint4(PK2(l2, one), PK2(one, nh), PK2(nl, 0), PK2(0, 0));
    }
}

// Pack one row-point into the lane's A-fragment half (kg = lane>>5).
__device__ __forceinline__ short8 packA(const float* __restrict__ p, int kg) {
    const unsigned short one = 0x3f80;
    float x0 = p[0], x1 = p[1], x2 = p[2];
    unsigned short h0 = f2bf(x0), h1 = f2bf(x1), h2 = f2bf(x2);
    unsigned short l0 = f2bf(x0 - bf2f(h0)), l1 = f2bf(x1 - bf2f(h1)), l2 = f2bf(x2 - bf2f(h2));
    unsigned short m0 = f2bf(-2.f * bf2f(h0)), m1 = f2bf(-2.f * bf2f(h1)), m2 = f2bf(-2.f * bf2f(h2));
    unsigned short q0 = f2bf(-2.f * bf2f(l0)), q1 = f2bf(-2.f * bf2f(l1)), q2 = f2bf(-2.f * bf2f(l2));
    float n = x0*x0 + x1*x1 + x2*x2;
    unsigned short nh = f2bf(n), nl = f2bf(n - bf2f(nh));
    short8 r;
    if (kg == 0) {
        r[0] = (short)m0; r[1] = (short)m1; r[2] = (short)m2; r[3] = (short)q0;
        r[4] = (short)q1; r[5] = (short)q2; r[6] = (short)m0; r[7] = (short)m1;
    } else {
        r[0] = (short)m2; r[1] = (short)nh; r[2] = (short)nl; r[3] = (short)one;
        r[4] = (short)one; r[5] = 0; r[6] = 0; r[7] = 0;
    }
    return r;
}

__global__ __launch_bounds__(THREADS, 4)   // 4 waves/EU, 2 blocks/CU, 128-reg cap
void cd_fused(const float* __restrict__ xyz1, const float* __restrict__ xyz2,
              const unsigned short* __restrict__ B1, const unsigned short* __restrict__ B2,
              float* __restrict__ out) {
    __shared__ unsigned short ysh[STAGEPTS * 16];   // 32 KB packed stage

    int bid = blockIdx.x;
    const int rb   = bid & (NROWBLK - 1);  bid >>= 6;
    const int b    = bid & (B_ - 1);       bid >>= 2;
    const int pass = bid;                   // 0: dist1 (rows=cloud1), 1: dist2

    const float* __restrict__ xa          = pass ? xyz2 : xyz1;   // row cloud
    const unsigned short* __restrict__ Bp = pass ? B1 : B2;       // scanned packed
    float* __restrict__ o = out + (size_t)pass * B_ * NPT;

    const int tid  = threadIdx.x;
    const int lane = tid & 63;
    const int w    = tid >> 6;             // 0..7
    const int rt   = w & 3;                // row-tile within block
    const int h    = w >> 2;               // column half (0 or 1)
    const int l31  = lane & 31;
    const int kg   = lane >> 5;

    const size_t bbase = (size_t)b * NPT;
    const int    myRow = rb * 128 + rt * 32;

    // In-register A fragment: lane packs its own row, keeps its k-half.
    short8 afrag = packA(xa + (bbase + myRow + l31) * 3, kg);

    f32x16 rmin;
    #pragma unroll
    for (int r = 0; r < 16; ++r) rmin[r] = __int_as_float(PINF_I);

    const unsigned short* __restrict__ gBb = Bp + bbase * 16;

    for (int s = 0; s < NSTAGE; ++s) {
        // DMA-stage 32 KB: 4 x global_load_lds(16B) per thread, pure copy.
        // LDS dest = wave-uniform base + lane*16 (HW rule); source matches.
        const unsigned short* gS = gBb + (size_t)s * STAGEPTS * 16;
        #pragma unroll
        for (int r = 0; r < 4; ++r) {
            const unsigned short* gp = gS + r * 4096 + w * 512 + lane * 8;
            unsigned short* lp = &ysh[r * 4096 + w * 512];
            __builtin_amdgcn_global_load_lds(
                (const __attribute__((address_space(1))) unsigned int*)gp,
                (__attribute__((address_space(3))) unsigned int*)lp, 16, 0, 0);
        }
        __syncthreads();   // drains vmcnt before barrier (compiler-inserted)

        // This wave's column half: 16 tiles = 8 min3 pairs of pure LDS compute.
        #pragma unroll
        for (int pr = 0; pr < 8; ++pr) {
            const int t0 = h * 16 + pr * 2;
            short8 bf0 = *(const short8*)(ysh + (size_t)t0 * 512 + kg * 256 + l31 * 8);
            short8 bf1 = *(const short8*)(ysh + (size_t)(t0 + 1) * 512 + kg * 256 + l31 * 8);
            f32x16 z = {0.f};
            f32x16 accX = __builtin_amdgcn_mfma_f32_32x32x16_bf16(afrag, bf0, z, 0, 0, 0);
            f32x16 accY = __builtin_amdgcn_mfma_f32_32x32x16_bf16(afrag, bf1, z, 0, 0, 0);
            #pragma unroll
            for (int r = 0; r < 16; ++r)
                rmin[r] = fminf(fminf(accX[r], accY[r]), rmin[r]);   // v_min3_f32
        }
        __syncthreads();
    }

    // Cross-half combine via LDS (reuse ysh; [rt][r][lane] = conflict-free).
    float* csh = (float*)ysh;              // 4 * 16 * 64 floats = 16 KB
    if (h == 1) {
        #pragma unroll
        for (int r = 0; r < 16; ++r)
            csh[rt * 1024 + r * 64 + lane] = rmin[r];
    }
    __syncthreads();
    if (h == 0) {
        #pragma unroll
        for (int r = 0; r < 16; ++r) {
            float v = fminf(rmin[r], csh[rt * 1024 + r * 64 + lane]);
            v = fminf(v, __shfl_xor(v, 1, 64));
            v = fminf(v, __shfl_xor(v, 2, 64));
            v = fminf(v, __shfl_xor(v, 4, 64));
            v = fminf(v, __shfl_xor(v, 8, 64));
            v = fminf(v, __shfl_xor(v, 16, 64));
            if (l31 == 0) {
                int row = myRow + (r & 3) + 8 * (r >> 2) + 4 * kg;
                o[bbase + row] = fmaxf(v, 0.f);
            }
        }
    }
}

extern "C" void kernel_launch(void* const* d_in, const int* in_sizes, int n_in,
                              void* d_out, int out_size, void* d_ws, size_t ws_size,
                              hipStream_t stream) {
    const float* xyz1 = (const float*)d_in[0];
    const float* xyz2 = (const float*)d_in[1];

    const size_t PSZ = (size_t)B_ * NPT * 16;       // ushorts per packed array
    unsigned short* B1 = (unsigned short*)d_ws;     // 1 MB
    unsigned short* B2 = B1 + PSZ;                  // 1 MB

    cd_packB<<<(B_ * NPT + 255) / 256, 256, 0, stream>>>(xyz1, xyz2, B1, B2);

    cd_fused<<<2 * B_ * NROWBLK, THREADS, 0, stream>>>(
        xyz1, xyz2, B1, B2, (float*)d_out);
}